// Round 1
// baseline (458.373 us; speedup 1.0000x reference)
//
#include <hip/hip_runtime.h>
#include <hip/hip_bf16.h>

// Problem constants: BS=8, Q=128, S1=32, S2=64, H=768, NH=12, DH=64.

typedef __attribute__((ext_vector_type(8))) short short8;
typedef __attribute__((ext_vector_type(4))) float f32x4;

__device__ __forceinline__ short f2bf(float f) {
  __hip_bfloat16 b = __float2bfloat16(f);
  return __builtin_bit_cast(short, b);
}
__device__ __forceinline__ float bf2f(short s) {
  __hip_bfloat16 b = __builtin_bit_cast(__hip_bfloat16, s);
  return __bfloat162float(b);
}

#define MFMA16(a, b, c) __builtin_amdgcn_mfma_f32_16x16x32_bf16((a), (b), (c), 0, 0, 0)

// ---------------------------------------------------------------------------
// Weight transpose: WT[n*768 + k] = bf16(W[k*768 + n])
// ---------------------------------------------------------------------------
__global__ __launch_bounds__(256)
void transpose_w(const float* __restrict__ W, short* __restrict__ WT) {
  __shared__ float tile[32][33];
  const int bx = blockIdx.x * 32, by = blockIdx.y * 32;
  const int tx = threadIdx.x, ty = threadIdx.y;  // block (32,8)
  #pragma unroll
  for (int i = 0; i < 32; i += 8)
    tile[ty + i][tx] = W[(size_t)(by + ty + i) * 768 + bx + tx];
  __syncthreads();
  #pragma unroll
  for (int i = 0; i < 32; i += 8)
    WT[(size_t)(bx + ty + i) * 768 + by + tx] = f2bf(tile[tx][ty + i]);
}

// ---------------------------------------------------------------------------
// Generic 128x128 bf16-MFMA GEMM: Out = A[M,768] @ W[768,768] + bias
//   A_BF16:   A is bf16 (else fp32, converted during staging)
//   OUT_BF16: output bf16 (else fp32)
//   VT_LAYOUT: store output transposed per (b,s,h): [b,s,h,d,t] (for v_proj)
// WT is the pre-transposed weight: WT[n][k].
// ---------------------------------------------------------------------------
template<int A_BF16, int OUT_BF16, int VT_LAYOUT>
__global__ __launch_bounds__(256)
void gemm128(const void* __restrict__ Ap, const short* __restrict__ WT,
             const float* __restrict__ bias, void* __restrict__ Outp, int M) {
  (void)M;
  const int K = 768, N = 768;
  __shared__ __align__(16) short As[128 * 40];  // pad 32->40: 2-way-free banks, 16B aligned
  __shared__ __align__(16) short Bs[128 * 40];
  const int tid = threadIdx.x;
  const int m0 = blockIdx.x * 128, n0 = blockIdx.y * 128;
  const int w = tid >> 6, lane = tid & 63, quad = lane >> 4, l16 = lane & 15;
  const int wm = (w >> 1) * 64, wn = (w & 1) * 64;
  const int srow = tid >> 1, soff = (tid & 1) * 16;

  const f32x4 zero4 = {0.f, 0.f, 0.f, 0.f};
  f32x4 acc[4][4];
  #pragma unroll
  for (int i = 0; i < 4; i++)
    #pragma unroll
    for (int j = 0; j < 4; j++) acc[i][j] = zero4;

  for (int k0 = 0; k0 < K; k0 += 32) {
    __syncthreads();
    // ---- stage A tile [128 x 32] ----
    if (A_BF16) {
      const short* src = (const short*)Ap + (size_t)(m0 + srow) * K + k0 + soff;
      *(short8*)&As[srow * 40 + soff]     = *(const short8*)src;
      *(short8*)&As[srow * 40 + soff + 8] = *(const short8*)(src + 8);
    } else {
      const float* src = (const float*)Ap + (size_t)(m0 + srow) * K + k0 + soff;
      float4 f0 = ((const float4*)src)[0];
      float4 f1 = ((const float4*)src)[1];
      float4 f2 = ((const float4*)src)[2];
      float4 f3 = ((const float4*)src)[3];
      __align__(16) short tmp[16] = {
          f2bf(f0.x), f2bf(f0.y), f2bf(f0.z), f2bf(f0.w),
          f2bf(f1.x), f2bf(f1.y), f2bf(f1.z), f2bf(f1.w),
          f2bf(f2.x), f2bf(f2.y), f2bf(f2.z), f2bf(f2.w),
          f2bf(f3.x), f2bf(f3.y), f2bf(f3.z), f2bf(f3.w)};
      *(short8*)&As[srow * 40 + soff]     = *(short8*)&tmp[0];
      *(short8*)&As[srow * 40 + soff + 8] = *(short8*)&tmp[8];
    }
    // ---- stage B tile [128 x 32] from WT rows (n-major, k contiguous) ----
    {
      const short* src = WT + (size_t)(n0 + srow) * K + k0 + soff;
      *(short8*)&Bs[srow * 40 + soff]     = *(const short8*)src;
      *(short8*)&Bs[srow * 40 + soff + 8] = *(const short8*)(src + 8);
    }
    __syncthreads();
    // ---- MFMA: wave computes 64x64 as 4x4 of 16x16, K=32 per call ----
    short8 af[4], bfg[4];
    #pragma unroll
    for (int i = 0; i < 4; i++)
      af[i] = *(short8*)&As[(wm + i * 16 + l16) * 40 + quad * 8];
    #pragma unroll
    for (int j = 0; j < 4; j++)
      bfg[j] = *(short8*)&Bs[(wn + j * 16 + l16) * 40 + quad * 8];
    #pragma unroll
    for (int i = 0; i < 4; i++)
      #pragma unroll
      for (int j = 0; j < 4; j++)
        acc[i][j] = MFMA16(af[i], bfg[j], acc[i][j]);
  }

  // ---- epilogue: C/D layout col=lane&15, row=quad*4+reg ----
  #pragma unroll
  for (int i = 0; i < 4; i++) {
    #pragma unroll
    for (int j = 0; j < 4; j++) {
      const int col = n0 + wn + j * 16 + l16;
      const float bv = bias[col];
      #pragma unroll
      for (int r = 0; r < 4; r++) {
        const int g = m0 + wm + i * 16 + quad * 4 + r;
        const float v = acc[i][j][r] + bv;
        if (VT_LAYOUT) {
          // g = (b*32+s)*64 + t ; col = h*64 + d  ->  [b,s,h,d,t]
          const int t = g & 63, bs_ = g >> 6, hh = col >> 6, dd = col & 63;
          ((short*)Outp)[(((size_t)bs_ * 12 + hh) * 64 + dd) * 64 + t] = f2bf(v);
        } else if (OUT_BF16) {
          ((short*)Outp)[(size_t)g * N + col] = f2bf(v);
        } else {
          ((float*)Outp)[(size_t)g * N + col] = v;
        }
      }
    }
  }
}

// ---------------------------------------------------------------------------
// Word-level attention, one block per (b, s, h):
//   S[q][t] = (Q Kt) * 0.125 ; softmax over t (+word mask) ; O = P V
//   Q-fragments read straight from global (L2-resident, 16B per lane).
// ---------------------------------------------------------------------------
__global__ __launch_bounds__(256)
void word_attn(const short* __restrict__ q_proj, const short* __restrict__ k_proj,
               const short* __restrict__ vT, const int* __restrict__ word_mask,
               short* __restrict__ wh) {
  __shared__ __align__(16) short KVs[128 * 72];  // K rows 0-63, Vt rows 64-127; O overlay
  __shared__ __align__(16) float Ss[128 * 65];   // S fp32; P bf16 overlay (stride 72)
  short* Ks = KVs;
  short* Vs = KVs + 64 * 72;
  short* Ps = (short*)Ss;
  short* Os = KVs;

  const int bid = blockIdx.x;
  const int h = bid % 12, s = (bid / 12) % 32, b = bid / (12 * 32);
  const int tid = threadIdx.x;
  const int w = tid >> 6, lane = tid & 63, quad = lane >> 4, l16 = lane & 15;
  const f32x4 zero4 = {0.f, 0.f, 0.f, 0.f};

  // ---- stage K (tid<128) and Vt (tid>=128): 64 rows x 64 bf16 each ----
  {
    const int t2 = tid & 127;
    const int row = t2 >> 1, half = (t2 & 1) * 32;
    const short* src;
    short* dst;
    if (tid < 128) {
      src = k_proj + ((size_t)((b * 32 + s) * 64 + row)) * 768 + h * 64 + half;
      dst = &Ks[row * 72 + half];
    } else {
      src = vT + ((size_t)((b * 32 + s) * 12 + h)) * 4096 + row * 64 + half;
      dst = &Vs[row * 72 + half];
    }
    #pragma unroll
    for (int i = 0; i < 4; i++)
      *(short8*)(dst + i * 8) = *(const short8*)(src + i * 8);
  }
  __syncthreads();

  // ---- S = Q Kt (wave w owns q rows 32w..32w+31) ----
  f32x4 sac[2][4];
  #pragma unroll
  for (int i = 0; i < 2; i++)
    #pragma unroll
    for (int j = 0; j < 4; j++) sac[i][j] = zero4;
  {
    short8 aq[2][2], bk[4][2];
    #pragma unroll
    for (int i = 0; i < 2; i++)
      #pragma unroll
      for (int kb = 0; kb < 2; kb++)
        aq[i][kb] = *(const short8*)(q_proj +
            ((size_t)(b * 128 + w * 32 + i * 16 + l16)) * 768 + h * 64 + kb * 32 + quad * 8);
    #pragma unroll
    for (int j = 0; j < 4; j++)
      #pragma unroll
      for (int kb = 0; kb < 2; kb++)
        bk[j][kb] = *(short8*)&Ks[(j * 16 + l16) * 72 + kb * 32 + quad * 8];
    #pragma unroll
    for (int i = 0; i < 2; i++)
      #pragma unroll
      for (int j = 0; j < 4; j++) {
        sac[i][j] = MFMA16(aq[i][0], bk[j][0], sac[i][j]);
        sac[i][j] = MFMA16(aq[i][1], bk[j][1], sac[i][j]);
      }
  }
  #pragma unroll
  for (int i = 0; i < 2; i++)
    #pragma unroll
    for (int j = 0; j < 4; j++)
      #pragma unroll
      for (int r = 0; r < 4; r++)
        Ss[(w * 32 + i * 16 + quad * 4 + r) * 65 + j * 16 + l16] = sac[i][j][r] * 0.125f;
  __syncthreads();

  // ---- softmax over t, 2 threads per row (adjacent lanes, shfl_xor 1) ----
  {
    const int row = tid >> 1, t0 = (tid & 1) * 32;
    const int* wmp = word_mask + (b * 32 + s) * 64 + t0;
    float vals[32];
    float mx = -3.0e38f;
    #pragma unroll
    for (int i = 0; i < 32; i++) {
      const float v = Ss[row * 65 + t0 + i] + (1.0f - (float)wmp[i]) * -10000.0f;
      vals[i] = v;
      mx = fmaxf(mx, v);
    }
    mx = fmaxf(mx, __shfl_xor(mx, 1));
    float sum = 0.f;
    #pragma unroll
    for (int i = 0; i < 32; i++) {
      const float e = __expf(vals[i] - mx);
      vals[i] = e;
      sum += e;
    }
    sum += __shfl_xor(sum, 1);
    const float inv = 1.0f / sum;
    __syncthreads();  // all Ss reads complete before P overlay write
    #pragma unroll
    for (int i = 0; i < 32; i++) Ps[row * 72 + t0 + i] = f2bf(vals[i] * inv);
  }
  __syncthreads();

  // ---- O = P V  (B-fragments from Vt rows = V columns) ----
  f32x4 oac[2][4];
  #pragma unroll
  for (int i = 0; i < 2; i++)
    #pragma unroll
    for (int j = 0; j < 4; j++) oac[i][j] = zero4;
  {
    short8 ap[2][2], bv[4][2];
    #pragma unroll
    for (int i = 0; i < 2; i++)
      #pragma unroll
      for (int kb = 0; kb < 2; kb++)
        ap[i][kb] = *(short8*)&Ps[(w * 32 + i * 16 + l16) * 72 + kb * 32 + quad * 8];
    #pragma unroll
    for (int j = 0; j < 4; j++)
      #pragma unroll
      for (int kb = 0; kb < 2; kb++)
        bv[j][kb] = *(short8*)&Vs[(j * 16 + l16) * 72 + kb * 32 + quad * 8];
    #pragma unroll
    for (int i = 0; i < 2; i++)
      #pragma unroll
      for (int j = 0; j < 4; j++) {
        oac[i][j] = MFMA16(ap[i][0], bv[j][0], oac[i][j]);
        oac[i][j] = MFMA16(ap[i][1], bv[j][1], oac[i][j]);
      }
  }
  __syncthreads();  // K/V reads complete before O overlay write
  #pragma unroll
  for (int i = 0; i < 2; i++)
    #pragma unroll
    for (int j = 0; j < 4; j++)
      #pragma unroll
      for (int r = 0; r < 4; r++)
        Os[(w * 32 + i * 16 + quad * 4 + r) * 72 + j * 16 + l16] = f2bf(oac[i][j][r]);
  __syncthreads();

  // ---- coalesced wh store: wh[((b*128+q)*32+s)*768 + h*64 + d] ----
  {
    const int row = tid >> 1, half = (tid & 1) * 32;
    short* dst = wh + (((size_t)(b * 128 + row)) * 32 + s) * 768 + h * 64 + half;
    const short* src = &Os[row * 72 + half];
    #pragma unroll
    for (int i = 0; i < 4; i++)
      *(short8*)(dst + i * 8) = *(const short8*)(src + i * 8);
  }
}

// ---------------------------------------------------------------------------
// Sentence-level attention + final output, one block per (b, q)
// ---------------------------------------------------------------------------
__global__ __launch_bounds__(256)
void sent_attn(const float* __restrict__ sq, const float* __restrict__ sk,
               const short* __restrict__ sv, const int* __restrict__ sent_mask,
               float* __restrict__ out) {
  __shared__ float sc[12 * 33];
  const int bid = blockIdx.x;
  const int b = bid >> 7, q = bid & 127;
  const int tid = threadIdx.x;

  // scores2[h][s] = sq[b,q,h,:].sk[b,s,h,:]*0.125 + sm
  for (int p = tid; p < 384; p += 256) {
    const int hh = p >> 5, ss = p & 31;
    const float* a = sq + ((size_t)(b * 128 + q)) * 768 + hh * 64;
    const float* c = sk + ((size_t)(b * 32 + ss)) * 768 + hh * 64;
    float d = 0.f;
    #pragma unroll
    for (int i = 0; i < 64; i++) d += a[i] * c[i];
    d = d * 0.125f + (1.0f - (float)sent_mask[(b * 128 + q) * 32 + ss]) * -10000.0f;
    sc[hh * 33 + ss] = d;
  }
  __syncthreads();
  if (tid < 12) {
    float mx = -3.0e38f;
    for (int ss = 0; ss < 32; ss++) mx = fmaxf(mx, sc[tid * 33 + ss]);
    float sum = 0.f;
    for (int ss = 0; ss < 32; ss++) {
      const float e = __expf(sc[tid * 33 + ss] - mx);
      sc[tid * 33 + ss] = e;
      sum += e;
    }
    const float inv = 1.0f / sum;
    for (int ss = 0; ss < 32; ss++) sc[tid * 33 + ss] *= inv;
  }
  __syncthreads();
  // out[b,q,h*64+d] = sum_s probs2[h][s] * sv[(b,q,s), h*64+d]
  for (int c = tid; c < 768; c += 256) {
    const int hh = c >> 6;
    const short* svp = sv + ((size_t)(b * 128 + q)) * 32 * 768 + c;
    float accv = 0.f;
    #pragma unroll
    for (int ss = 0; ss < 32; ss++) accv += sc[hh * 33 + ss] * bf2f(svp[(size_t)ss * 768]);
    out[((size_t)(b * 128 + q)) * 768 + c] = accv;
  }
}

// ---------------------------------------------------------------------------
extern "C" void kernel_launch(void* const* d_in, const int* in_sizes, int n_in,
                              void* d_out, int out_size, void* d_ws, size_t ws_size,
                              hipStream_t stream) {
  (void)in_sizes; (void)n_in; (void)out_size; (void)ws_size;
  const float* q_in      = (const float*)d_in[0];   // [8,128,768]
  const float* k_in      = (const float*)d_in[1];   // [8,32,64,768]
  const float* v_in      = (const float*)d_in[2];   // [8,32,64,768]
  const float* kvec      = (const float*)d_in[3];   // [8,32,768]
  const int*   word_mask = (const int*)d_in[4];     // [8,32,64]
  const int*   sent_mask = (const int*)d_in[5];     // [1024,32]
  const float* wq_w = (const float*)d_in[6],  *wq_b = (const float*)d_in[7];
  const float* wk_w = (const float*)d_in[8],  *wk_b = (const float*)d_in[9];
  const float* wv_w = (const float*)d_in[10], *wv_b = (const float*)d_in[11];
  const float* sq_w = (const float*)d_in[12], *sq_b = (const float*)d_in[13];
  const float* sk_w = (const float*)d_in[14], *sk_b = (const float*)d_in[15];
  const float* sv_w = (const float*)d_in[16], *sv_b = (const float*)d_in[17];
  float* out = (float*)d_out;

  char* ws = (char*)d_ws;
  size_t off = 0;
  auto alloc = [&](size_t bytes) -> void* {
    void* p = ws + off;
    off += (bytes + 255) & ~(size_t)255;
    return p;
  };
  short* WT  = (short*)alloc((size_t)6 * 768 * 768 * 2);   //  7.1 MB
  short* qp  = (short*)alloc((size_t)1024 * 768 * 2);      //  1.6 MB
  short* kp  = (short*)alloc((size_t)16384 * 768 * 2);     // 25.2 MB
  short* vT  = (short*)alloc((size_t)16384 * 768 * 2);     // 25.2 MB  [b,s,h,d,t]
  float* sqp = (float*)alloc((size_t)1024 * 768 * 4);      //  3.1 MB
  float* skp = (float*)alloc((size_t)256 * 768 * 4);       //  0.8 MB
  short* wh  = (short*)alloc((size_t)32768 * 768 * 2);     // 50.3 MB
  short* sv  = (short*)alloc((size_t)32768 * 768 * 2);     // 50.3 MB

  const int WELEM = 768 * 768;
  dim3 tB(32, 8), tG(24, 24);
  transpose_w<<<tG, tB, 0, stream>>>(wq_w, WT + 0 * WELEM);
  transpose_w<<<tG, tB, 0, stream>>>(wk_w, WT + 1 * WELEM);
  transpose_w<<<tG, tB, 0, stream>>>(wv_w, WT + 2 * WELEM);
  transpose_w<<<tG, tB, 0, stream>>>(sq_w, WT + 3 * WELEM);
  transpose_w<<<tG, tB, 0, stream>>>(sk_w, WT + 4 * WELEM);
  transpose_w<<<tG, tB, 0, stream>>>(sv_w, WT + 5 * WELEM);

  // projections
  gemm128<0, 1, 0><<<dim3(8, 6),   256, 0, stream>>>(q_in, WT + 0 * WELEM, wq_b, qp, 1024);
  gemm128<0, 1, 0><<<dim3(128, 6), 256, 0, stream>>>(k_in, WT + 1 * WELEM, wk_b, kp, 16384);
  gemm128<0, 1, 1><<<dim3(128, 6), 256, 0, stream>>>(v_in, WT + 2 * WELEM, wv_b, vT, 16384);
  gemm128<0, 0, 0><<<dim3(8, 6),   256, 0, stream>>>(q_in, WT + 3 * WELEM, sq_b, sqp, 1024);
  gemm128<0, 0, 0><<<dim3(2, 6),   256, 0, stream>>>(kvec, WT + 4 * WELEM, sk_b, skp, 256);

  // word-level attention -> wh [ (b,q,s), 768 ] bf16
  word_attn<<<dim3(3072), 256, 0, stream>>>(qp, kp, vT, word_mask, wh);

  // sv = wh @ sv_w + sv_b   (the big GEMM)
  gemm128<1, 1, 0><<<dim3(256, 6), 256, 0, stream>>>(wh, WT + 5 * WELEM, sv_b, sv, 32768);

  // sentence attention + output
  sent_attn<<<dim3(1024), 256, 0, stream>>>(sqp, skp, sv, sent_mask, out);
}

// Round 2
// 389.703 us; speedup vs baseline: 1.1762x; 1.1762x over previous
//
#include <hip/hip_runtime.h>
#include <hip/hip_bf16.h>

// Problem constants: BS=8, Q=128, S1=32, S2=64, H=768, NH=12, DH=64.

typedef __attribute__((ext_vector_type(8))) short short8;
typedef __attribute__((ext_vector_type(4))) float f32x4;

__device__ __forceinline__ short f2bf(float f) {
  __hip_bfloat16 b = __float2bfloat16(f);
  return __builtin_bit_cast(short, b);
}
__device__ __forceinline__ float bf2f(short s) {
  __hip_bfloat16 b = __builtin_bit_cast(__hip_bfloat16, s);
  return __bfloat162float(b);
}

#define MFMA16(a, b, c) __builtin_amdgcn_mfma_f32_16x16x32_bf16((a), (b), (c), 0, 0, 0)

// async 16B/lane global->LDS (wave-uniform LDS base; HW adds lane*16)
__device__ __forceinline__ void async_load16(const short* g, short* l) {
  auto l3 = (__attribute__((address_space(3))) short*)(uintptr_t)(
      reinterpret_cast<uintptr_t>(l));
  auto g1 = (const __attribute__((address_space(1))) short*)g;
  __builtin_amdgcn_global_load_lds((const __attribute__((address_space(1))) void*)g1,
                                   (__attribute__((address_space(3))) void*)l3, 16, 0, 0);
}

// ---------------------------------------------------------------------------
// fp32 -> bf16 bulk convert (8 elems/thread)
// ---------------------------------------------------------------------------
__global__ __launch_bounds__(256)
void cvt_bf16(const float* __restrict__ src, short* __restrict__ dst, int n8) {
  const int i = blockIdx.x * 256 + threadIdx.x;
  if (i >= n8) return;
  const float4* s = (const float4*)src + (size_t)i * 2;
  const float4 a = s[0], b = s[1];
  __align__(16) short tmp[8] = {f2bf(a.x), f2bf(a.y), f2bf(a.z), f2bf(a.w),
                                f2bf(b.x), f2bf(b.y), f2bf(b.z), f2bf(b.w)};
  *((short8*)dst + i) = *(short8*)tmp;
}

// ---------------------------------------------------------------------------
// All six weight transposes in one launch. Slot order (n-major concat):
//   0:wq 1:sq 2:wk 3:wv 4:sk 5:sv   -> WT[slot*768 + n][k]
// ---------------------------------------------------------------------------
__global__ __launch_bounds__(256)
void transpose_w6(const float* __restrict__ w0, const float* __restrict__ w1,
                  const float* __restrict__ w2, const float* __restrict__ w3,
                  const float* __restrict__ w4, const float* __restrict__ w5,
                  short* __restrict__ WT) {
  __shared__ float tile[32][33];
  const float* Ws[6] = {w0, w1, w2, w3, w4, w5};
  const float* W = Ws[blockIdx.z];
  short* WTo = WT + (size_t)blockIdx.z * 768 * 768;
  const int bx = blockIdx.x * 32, by = blockIdx.y * 32;
  const int tx = threadIdx.x, ty = threadIdx.y;  // block (32,8)
  #pragma unroll
  for (int i = 0; i < 32; i += 8)
    tile[ty + i][tx] = W[(size_t)(by + ty + i) * 768 + bx + tx];
  __syncthreads();
  #pragma unroll
  for (int i = 0; i < 32; i += 8)
    WTo[(size_t)(bx + ty + i) * 768 + by + tx] = f2bf(tile[tx][ty + i]);
}

// ---------------------------------------------------------------------------
// m97-style GEMM: Out = A[M,768] @ W + bias, A bf16, WT[n][k] bf16.
// 128x128 tile, BK=32, async global_load_lds staging, unpadded LDS.
// OUT_MODE: 0 = fp32 row-major      (sk proj)
//           1 = bf16 row-major      (k proj, sv proj)
//           2 = bf16 vT layout      (v proj: [b,s,h,d,t])
//           3 = split qp(bf16)/sqp(fp32) over N=1536 (q+sq proj)
// ---------------------------------------------------------------------------
template<int OUT_MODE>
__global__ __launch_bounds__(256)
void gemm_lds(const short* __restrict__ A, const short* __restrict__ WT,
              const float* __restrict__ bias, const float* __restrict__ bias2,
              void* __restrict__ Outp, void* __restrict__ Outp2) {
  const int K = 768, N = 768;
  __shared__ __align__(16) short As[128 * 32];  // unpadded: required by lds-dma
  __shared__ __align__(16) short Bs[128 * 32];
  const int tid = threadIdx.x;
  const int m0 = blockIdx.x * 128, n0 = blockIdx.y * 128;
  const int w = tid >> 6, lane = tid & 63, quad = lane >> 4, l16 = lane & 15;
  const int wm = (w >> 1) * 64, wn = (w & 1) * 64;

  // staging: wave w covers rows [w*32, w*32+32) in two 16-row instructions
  const int grow = w * 32 + (lane >> 2);
  const int kc = (lane & 3) * 8;
  const short* ag = A + (size_t)(m0 + grow) * K + kc;
  const short* bg = WT + (size_t)(n0 + grow) * K + kc;
  short* al = &As[(w * 32) * 32];
  short* bl = &Bs[(w * 32) * 32];

  const f32x4 zero4 = {0.f, 0.f, 0.f, 0.f};
  f32x4 acc[4][4];
  #pragma unroll
  for (int i = 0; i < 4; i++)
    #pragma unroll
    for (int j = 0; j < 4; j++) acc[i][j] = zero4;

  for (int k0 = 0; k0 < K; k0 += 32) {
    __syncthreads();
    async_load16(ag, al);
    async_load16(ag + (size_t)16 * K, al + 16 * 32);
    async_load16(bg, bl);
    async_load16(bg + (size_t)16 * K, bl + 16 * 32);
    ag += 32;
    bg += 32;
    __syncthreads();
    short8 af[4], bf[4];
    #pragma unroll
    for (int i = 0; i < 4; i++)
      af[i] = *(short8*)&As[(wm + i * 16 + l16) * 32 + quad * 8];
    #pragma unroll
    for (int j = 0; j < 4; j++)
      bf[j] = *(short8*)&Bs[(wn + j * 16 + l16) * 32 + quad * 8];
    #pragma unroll
    for (int i = 0; i < 4; i++)
      #pragma unroll
      for (int j = 0; j < 4; j++)
        acc[i][j] = MFMA16(af[i], bf[j], acc[i][j]);
  }

  // ---- epilogue: C/D layout col=lane&15, row=quad*4+reg ----
  #pragma unroll
  for (int i = 0; i < 4; i++) {
    #pragma unroll
    for (int j = 0; j < 4; j++) {
      const int col = n0 + wn + j * 16 + l16;
      float bv;
      if (OUT_MODE == 3)
        bv = (col < 768) ? bias[col] : bias2[col - 768];
      else
        bv = bias[col];
      #pragma unroll
      for (int r = 0; r < 4; r++) {
        const int g = m0 + wm + i * 16 + quad * 4 + r;
        const float v = acc[i][j][r] + bv;
        if (OUT_MODE == 2) {
          // g = (b*32+s)*64 + t ; col = h*64 + d  ->  [b,s,h,d,t]
          const int t = g & 63, bs_ = g >> 6, hh = col >> 6, dd = col & 63;
          ((short*)Outp)[(((size_t)bs_ * 12 + hh) * 64 + dd) * 64 + t] = f2bf(v);
        } else if (OUT_MODE == 1) {
          ((short*)Outp)[(size_t)g * N + col] = f2bf(v);
        } else if (OUT_MODE == 0) {
          ((float*)Outp)[(size_t)g * N + col] = v;
        } else {  // 3
          if (col < 768)
            ((short*)Outp)[(size_t)g * 768 + col] = f2bf(v);
          else
            ((float*)Outp2)[(size_t)g * 768 + (col - 768)] = v;
        }
      }
    }
  }
}

// ---------------------------------------------------------------------------
// Word-level attention, one block per (b, s, h):
//   S[q][t] = (Q Kt) * 0.125 ; softmax over t (+word mask) ; O = P V
// ---------------------------------------------------------------------------
__global__ __launch_bounds__(256)
void word_attn(const short* __restrict__ q_proj, const short* __restrict__ k_proj,
               const short* __restrict__ vT, const int* __restrict__ word_mask,
               short* __restrict__ wh) {
  __shared__ __align__(16) short KVs[128 * 72];  // K rows 0-63, Vt rows 64-127; O overlay
  __shared__ __align__(16) float Ss[128 * 65];   // S fp32; P bf16 overlay (stride 72)
  short* Ks = KVs;
  short* Vs = KVs + 64 * 72;
  short* Ps = (short*)Ss;
  short* Os = KVs;

  const int bid = blockIdx.x;
  const int h = bid % 12, s = (bid / 12) % 32, b = bid / (12 * 32);
  const int tid = threadIdx.x;
  const int w = tid >> 6, lane = tid & 63, quad = lane >> 4, l16 = lane & 15;
  const f32x4 zero4 = {0.f, 0.f, 0.f, 0.f};

  {
    const int t2 = tid & 127;
    const int row = t2 >> 1, half = (t2 & 1) * 32;
    const short* src;
    short* dst;
    if (tid < 128) {
      src = k_proj + ((size_t)((b * 32 + s) * 64 + row)) * 768 + h * 64 + half;
      dst = &Ks[row * 72 + half];
    } else {
      src = vT + ((size_t)((b * 32 + s) * 12 + h)) * 4096 + row * 64 + half;
      dst = &Vs[row * 72 + half];
    }
    #pragma unroll
    for (int i = 0; i < 4; i++)
      *(short8*)(dst + i * 8) = *(const short8*)(src + i * 8);
  }
  __syncthreads();

  f32x4 sac[2][4];
  #pragma unroll
  for (int i = 0; i < 2; i++)
    #pragma unroll
    for (int j = 0; j < 4; j++) sac[i][j] = zero4;
  {
    short8 aq[2][2], bk[4][2];
    #pragma unroll
    for (int i = 0; i < 2; i++)
      #pragma unroll
      for (int kb = 0; kb < 2; kb++)
        aq[i][kb] = *(const short8*)(q_proj +
            ((size_t)(b * 128 + w * 32 + i * 16 + l16)) * 768 + h * 64 + kb * 32 + quad * 8);
    #pragma unroll
    for (int j = 0; j < 4; j++)
      #pragma unroll
      for (int kb = 0; kb < 2; kb++)
        bk[j][kb] = *(short8*)&Ks[(j * 16 + l16) * 72 + kb * 32 + quad * 8];
    #pragma unroll
    for (int i = 0; i < 2; i++)
      #pragma unroll
      for (int j = 0; j < 4; j++) {
        sac[i][j] = MFMA16(aq[i][0], bk[j][0], sac[i][j]);
        sac[i][j] = MFMA16(aq[i][1], bk[j][1], sac[i][j]);
      }
  }
  #pragma unroll
  for (int i = 0; i < 2; i++)
    #pragma unroll
    for (int j = 0; j < 4; j++)
      #pragma unroll
      for (int r = 0; r < 4; r++)
        Ss[(w * 32 + i * 16 + quad * 4 + r) * 65 + j * 16 + l16] = sac[i][j][r] * 0.125f;
  __syncthreads();

  {
    const int row = tid >> 1, t0 = (tid & 1) * 32;
    const int* wmp = word_mask + (b * 32 + s) * 64 + t0;
    float vals[32];
    float mx = -3.0e38f;
    #pragma unroll
    for (int i = 0; i < 32; i++) {
      const float v = Ss[row * 65 + t0 + i] + (1.0f - (float)wmp[i]) * -10000.0f;
      vals[i] = v;
      mx = fmaxf(mx, v);
    }
    mx = fmaxf(mx, __shfl_xor(mx, 1));
    float sum = 0.f;
    #pragma unroll
    for (int i = 0; i < 32; i++) {
      const float e = __expf(vals[i] - mx);
      vals[i] = e;
      sum += e;
    }
    sum += __shfl_xor(sum, 1);
    const float inv = 1.0f / sum;
    __syncthreads();
    #pragma unroll
    for (int i = 0; i < 32; i++) Ps[row * 72 + t0 + i] = f2bf(vals[i] * inv);
  }
  __syncthreads();

  f32x4 oac[2][4];
  #pragma unroll
  for (int i = 0; i < 2; i++)
    #pragma unroll
    for (int j = 0; j < 4; j++) oac[i][j] = zero4;
  {
    short8 ap[2][2], bv[4][2];
    #pragma unroll
    for (int i = 0; i < 2; i++)
      #pragma unroll
      for (int kb = 0; kb < 2; kb++)
        ap[i][kb] = *(short8*)&Ps[(w * 32 + i * 16 + l16) * 72 + kb * 32 + quad * 8];
    #pragma unroll
    for (int j = 0; j < 4; j++)
      #pragma unroll
      for (int kb = 0; kb < 2; kb++)
        bv[j][kb] = *(short8*)&Vs[(j * 16 + l16) * 72 + kb * 32 + quad * 8];
    #pragma unroll
    for (int i = 0; i < 2; i++)
      #pragma unroll
      for (int j = 0; j < 4; j++) {
        oac[i][j] = MFMA16(ap[i][0], bv[j][0], oac[i][j]);
        oac[i][j] = MFMA16(ap[i][1], bv[j][1], oac[i][j]);
      }
  }
  __syncthreads();
  #pragma unroll
  for (int i = 0; i < 2; i++)
    #pragma unroll
    for (int j = 0; j < 4; j++)
      #pragma unroll
      for (int r = 0; r < 4; r++)
        Os[(w * 32 + i * 16 + quad * 4 + r) * 72 + j * 16 + l16] = f2bf(oac[i][j][r]);
  __syncthreads();

  {
    const int row = tid >> 1, half = (tid & 1) * 32;
    short* dst = wh + (((size_t)(b * 128 + row)) * 32 + s) * 768 + h * 64 + half;
    const short* src = &Os[row * 72 + half];
    #pragma unroll
    for (int i = 0; i < 4; i++)
      *(short8*)(dst + i * 8) = *(const short8*)(src + i * 8);
  }
}

// ---------------------------------------------------------------------------
// Sentence-level attention + final output, one block per (b, q)
// ---------------------------------------------------------------------------
__global__ __launch_bounds__(256)
void sent_attn(const float* __restrict__ sq, const float* __restrict__ sk,
               const short* __restrict__ sv, const int* __restrict__ sent_mask,
               float* __restrict__ out) {
  __shared__ float sc[12 * 33];
  const int bid = blockIdx.x;
  const int b = bid >> 7, q = bid & 127;
  const int tid = threadIdx.x;

  for (int p = tid; p < 384; p += 256) {
    const int hh = p >> 5, ss = p & 31;
    const float* a = sq + ((size_t)(b * 128 + q)) * 768 + hh * 64;
    const float* c = sk + ((size_t)(b * 32 + ss)) * 768 + hh * 64;
    float d = 0.f;
    #pragma unroll
    for (int i = 0; i < 64; i++) d += a[i] * c[i];
    d = d * 0.125f + (1.0f - (float)sent_mask[(b * 128 + q) * 32 + ss]) * -10000.0f;
    sc[hh * 33 + ss] = d;
  }
  __syncthreads();
  if (tid < 12) {
    float mx = -3.0e38f;
    for (int ss = 0; ss < 32; ss++) mx = fmaxf(mx, sc[tid * 33 + ss]);
    float sum = 0.f;
    for (int ss = 0; ss < 32; ss++) {
      const float e = __expf(sc[tid * 33 + ss] - mx);
      sc[tid * 33 + ss] = e;
      sum += e;
    }
    const float inv = 1.0f / sum;
    for (int ss = 0; ss < 32; ss++) sc[tid * 33 + ss] *= inv;
  }
  __syncthreads();
  for (int c = tid; c < 768; c += 256) {
    const int hh = c >> 6;
    const short* svp = sv + ((size_t)(b * 128 + q)) * 32 * 768 + c;
    float accv = 0.f;
    #pragma unroll
    for (int ss = 0; ss < 32; ss++) accv += sc[hh * 33 + ss] * bf2f(svp[(size_t)ss * 768]);
    out[((size_t)(b * 128 + q)) * 768 + c] = accv;
  }
}

// ---------------------------------------------------------------------------
extern "C" void kernel_launch(void* const* d_in, const int* in_sizes, int n_in,
                              void* d_out, int out_size, void* d_ws, size_t ws_size,
                              hipStream_t stream) {
  (void)in_sizes; (void)n_in; (void)out_size; (void)ws_size;
  const float* q_in      = (const float*)d_in[0];   // [8,128,768]
  const float* k_in      = (const float*)d_in[1];   // [8,32,64,768]
  const float* v_in      = (const float*)d_in[2];   // [8,32,64,768]
  const float* kvec      = (const float*)d_in[3];   // [8,32,768]
  const int*   word_mask = (const int*)d_in[4];     // [8,32,64]
  const int*   sent_mask = (const int*)d_in[5];     // [1024,32]
  const float* wq_w = (const float*)d_in[6],  *wq_b = (const float*)d_in[7];
  const float* wk_w = (const float*)d_in[8],  *wk_b = (const float*)d_in[9];
  const float* wv_w = (const float*)d_in[10], *wv_b = (const float*)d_in[11];
  const float* sq_w = (const float*)d_in[12], *sq_b = (const float*)d_in[13];
  const float* sk_w = (const float*)d_in[14], *sk_b = (const float*)d_in[15];
  const float* sv_w = (const float*)d_in[16], *sv_b = (const float*)d_in[17];
  float* out = (float*)d_out;

  char* ws = (char*)d_ws;
  size_t off = 0;
  auto alloc = [&](size_t bytes) -> void* {
    void* p = ws + off;
    off += (bytes + 255) & ~(size_t)255;
    return p;
  };
  short* WT  = (short*)alloc((size_t)6 * 768 * 768 * 2);   //  7.1 MB (slots: wq,sq,wk,wv,sk,sv)
  short* qbf = (short*)alloc((size_t)1024 * 768 * 2);      //  1.6 MB
  short* kbf = (short*)alloc((size_t)16384 * 768 * 2);     // 25.2 MB
  short* vbf = (short*)alloc((size_t)16384 * 768 * 2);     // 25.2 MB
  short* kvb = (short*)alloc((size_t)256 * 768 * 2);       //  0.4 MB
  short* qp  = (short*)alloc((size_t)1024 * 768 * 2);      //  1.6 MB
  short* kp  = (short*)alloc((size_t)16384 * 768 * 2);     // 25.2 MB
  short* vT  = (short*)alloc((size_t)16384 * 768 * 2);     // 25.2 MB  [b,s,h,d,t]
  float* sqp = (float*)alloc((size_t)1024 * 768 * 4);      //  3.1 MB
  float* skp = (float*)alloc((size_t)256 * 768 * 4);       //  0.8 MB
  short* wh  = (short*)alloc((size_t)32768 * 768 * 2);     // 50.3 MB
  short* sv  = (short*)alloc((size_t)32768 * 768 * 2);     // 50.3 MB

  const int WELEM = 768 * 768;

  // weight transposes (slot order: wq, sq, wk, wv, sk, sv)
  transpose_w6<<<dim3(24, 24, 6), dim3(32, 8), 0, stream>>>(
      wq_w, sq_w, wk_w, wv_w, sk_w, sv_w, WT);

  // fp32 -> bf16 activation converts
  cvt_bf16<<<dim3(786432 / 8 / 256), 256, 0, stream>>>(q_in, qbf, 786432 / 8);
  cvt_bf16<<<dim3(12582912 / 8 / 256), 256, 0, stream>>>(k_in, kbf, 12582912 / 8);
  cvt_bf16<<<dim3(12582912 / 8 / 256), 256, 0, stream>>>(v_in, vbf, 12582912 / 8);
  cvt_bf16<<<dim3(196608 / 8 / 256), 256, 0, stream>>>(kvec, kvb, 196608 / 8);

  // projections (m97-style async-staged GEMMs)
  gemm_lds<3><<<dim3(8, 12), 256, 0, stream>>>(qbf, WT + 0 * WELEM, wq_b, sq_b, qp, sqp);
  gemm_lds<1><<<dim3(128, 6), 256, 0, stream>>>(kbf, WT + 2 * WELEM, wk_b, nullptr, kp, nullptr);
  gemm_lds<2><<<dim3(128, 6), 256, 0, stream>>>(vbf, WT + 3 * WELEM, wv_b, nullptr, vT, nullptr);
  gemm_lds<0><<<dim3(2, 6), 256, 0, stream>>>(kvb, WT + 4 * WELEM, sk_b, nullptr, skp, nullptr);

  // word-level attention -> wh [ (b,q,s), 768 ] bf16
  word_attn<<<dim3(3072), 256, 0, stream>>>(qp, kp, vT, word_mask, wh);

  // sv = wh @ sv_w + sv_b   (the big GEMM)
  gemm_lds<1><<<dim3(256, 6), 256, 0, stream>>>(wh, WT + 5 * WELEM, sv_b, nullptr, sv, nullptr);

  // sentence attention + output
  sent_attn<<<dim3(1024), 256, 0, stream>>>(sqp, skp, sv, sent_mask, out);
}

// Round 3
// 367.677 us; speedup vs baseline: 1.2467x; 1.0599x over previous
//
#include <hip/hip_runtime.h>
#include <hip/hip_bf16.h>

// Problem constants: BS=8, Q=128, S1=32, S2=64, H=768, NH=12, DH=64.

typedef __attribute__((ext_vector_type(8))) short short8;
typedef __attribute__((ext_vector_type(4))) short short4v;
typedef __attribute__((ext_vector_type(4))) float f32x4;

__device__ __forceinline__ short f2bf(float f) {
  __hip_bfloat16 b = __float2bfloat16(f);
  return __builtin_bit_cast(short, b);
}
__device__ __forceinline__ float bf2f(short s) {
  __hip_bfloat16 b = __builtin_bit_cast(__hip_bfloat16, s);
  return __bfloat162float(b);
}

#define MFMA16(a, b, c) __builtin_amdgcn_mfma_f32_16x16x32_bf16((a), (b), (c), 0, 0, 0)

// async 16B/lane global->LDS (wave-uniform LDS base; HW adds lane*16)
__device__ __forceinline__ void async_load16(const short* g, short* l) {
  auto l3 = (__attribute__((address_space(3))) short*)(uintptr_t)(
      reinterpret_cast<uintptr_t>(l));
  auto g1 = (const __attribute__((address_space(1))) short*)g;
  __builtin_amdgcn_global_load_lds((const __attribute__((address_space(1))) void*)g1,
                                   (__attribute__((address_space(3))) void*)l3, 16, 0, 0);
}

// ---------------------------------------------------------------------------
// fp32 -> bf16 bulk convert, all four activation tensors in one launch.
// Ranges in short8 units: q 98304 | k 1572864 | v 1572864 | kvec 24576.
// ---------------------------------------------------------------------------
__global__ __launch_bounds__(256)
void cvt_all(const float* __restrict__ q_in, const float* __restrict__ k_in,
             const float* __restrict__ v_in, const float* __restrict__ kvec,
             short* __restrict__ qbf, short* __restrict__ kbf,
             short* __restrict__ vbf, short* __restrict__ kvb) {
  const int i = blockIdx.x * 256 + threadIdx.x;
  const float* src;
  short* dst;
  int idx;
  if (i < 98304)        { src = q_in; dst = qbf; idx = i; }
  else if (i < 1671168) { src = k_in; dst = kbf; idx = i - 98304; }
  else if (i < 3244032) { src = v_in; dst = vbf; idx = i - 1671168; }
  else if (i < 3268608) { src = kvec; dst = kvb; idx = i - 3244032; }
  else return;
  const float4* s = (const float4*)src + (size_t)idx * 2;
  const float4 a = s[0], b = s[1];
  __align__(16) short tmp[8] = {f2bf(a.x), f2bf(a.y), f2bf(a.z), f2bf(a.w),
                                f2bf(b.x), f2bf(b.y), f2bf(b.z), f2bf(b.w)};
  *((short8*)dst + idx) = *(short8*)tmp;
}

// ---------------------------------------------------------------------------
// All six weight transposes in one launch. Slot order (n-major concat):
//   0:wq 1:sq 2:wk 3:wv 4:sk 5:sv   -> WT[slot*768 + n][k]
// ---------------------------------------------------------------------------
__global__ __launch_bounds__(256)
void transpose_w6(const float* __restrict__ w0, const float* __restrict__ w1,
                  const float* __restrict__ w2, const float* __restrict__ w3,
                  const float* __restrict__ w4, const float* __restrict__ w5,
                  short* __restrict__ WT) {
  __shared__ float tile[32][33];
  const float* Ws[6] = {w0, w1, w2, w3, w4, w5};
  const float* W = Ws[blockIdx.z];
  short* WTo = WT + (size_t)blockIdx.z * 768 * 768;
  const int bx = blockIdx.x * 32, by = blockIdx.y * 32;
  const int tx = threadIdx.x, ty = threadIdx.y;  // block (32,8)
  #pragma unroll
  for (int i = 0; i < 32; i += 8)
    tile[ty + i][tx] = W[(size_t)(by + ty + i) * 768 + bx + tx];
  __syncthreads();
  #pragma unroll
  for (int i = 0; i < 32; i += 8)
    WTo[(size_t)(bx + ty + i) * 768 + by + tx] = f2bf(tile[tx][ty + i]);
}

// ---------------------------------------------------------------------------
// m97-style GEMM core: 128x128 tile, BK=32, async global_load_lds staging.
// OUT_MODE: 0 = fp32 row-major                       (sk proj)
//           3 = split qp(bf16)/sqp(fp32) over N=1536 (q+sq proj)
//           4 = fused sentence-attn contraction      (sv proj -> out)
// ---------------------------------------------------------------------------
template<int OUT_MODE>
__global__ __launch_bounds__(256)
void gemm_lds(const short* __restrict__ A, const short* __restrict__ WT,
              const float* __restrict__ bias, const float* __restrict__ bias2,
              const float* __restrict__ probs2, void* __restrict__ Outp,
              void* __restrict__ Outp2) {
  const int K = 768;
  __shared__ __align__(16) short As[128 * 32];  // unpadded: required by lds-dma
  __shared__ __align__(16) short Bs[128 * 32];
  const int tid = threadIdx.x;
  const int m0 = blockIdx.x * 128, n0 = blockIdx.y * 128;
  const int w = tid >> 6, lane = tid & 63, quad = lane >> 4, l16 = lane & 15;
  const int wm = (w >> 1) * 64, wn = (w & 1) * 64;

  const int grow = w * 32 + (lane >> 2);
  const int kc = (lane & 3) * 8;
  const short* ag = A + (size_t)(m0 + grow) * K + kc;
  const short* bg = WT + (size_t)(n0 + grow) * K + kc;
  short* al = &As[(w * 32) * 32];
  short* bl = &Bs[(w * 32) * 32];

  const f32x4 zero4 = {0.f, 0.f, 0.f, 0.f};
  f32x4 acc[4][4];
  #pragma unroll
  for (int i = 0; i < 4; i++)
    #pragma unroll
    for (int j = 0; j < 4; j++) acc[i][j] = zero4;

  for (int k0 = 0; k0 < K; k0 += 32) {
    __syncthreads();
    async_load16(ag, al);
    async_load16(ag + (size_t)16 * K, al + 16 * 32);
    async_load16(bg, bl);
    async_load16(bg + (size_t)16 * K, bl + 16 * 32);
    ag += 32;
    bg += 32;
    __syncthreads();
    short8 af[4], bf[4];
    #pragma unroll
    for (int i = 0; i < 4; i++)
      af[i] = *(short8*)&As[(wm + i * 16 + l16) * 32 + quad * 8];
    #pragma unroll
    for (int j = 0; j < 4; j++)
      bf[j] = *(short8*)&Bs[(wn + j * 16 + l16) * 32 + quad * 8];
    #pragma unroll
    for (int i = 0; i < 4; i++)
      #pragma unroll
      for (int j = 0; j < 4; j++)
        acc[i][j] = MFMA16(af[i], bf[j], acc[i][j]);
  }

  if (OUT_MODE == 4) {
    // ---- fused sentence attention ----
    // row g = m0+wm+i*16+quad*4+r -> bq = g>>5 = bq0+(i>>1), s = (i&1)*16+quad*4+r
    // col = n0+wn+j*16+l16 -> head h = (n0+wn)>>6 (wave-constant)
    // out[bq,col] = sum_s probs2[bq,h,s]*acc + bias[col]   (sum_s probs2 = 1)
    const int h = (n0 + wn) >> 6;
    const int bq0 = (m0 + wm) >> 5;
    float p2[2][2][4];  // [group][i&1][r]
    #pragma unroll
    for (int g2 = 0; g2 < 2; g2++)
      #pragma unroll
      for (int par = 0; par < 2; par++)
        #pragma unroll
        for (int r = 0; r < 4; r++)
          p2[g2][par][r] =
              probs2[((size_t)(bq0 + g2) * 12 + h) * 32 + par * 16 + quad * 4 + r];
    float red[4][2];
    #pragma unroll
    for (int j = 0; j < 4; j++)
      #pragma unroll
      for (int g2 = 0; g2 < 2; g2++) {
        float ps = 0.f;
        #pragma unroll
        for (int par = 0; par < 2; par++)
          #pragma unroll
          for (int r = 0; r < 4; r++)
            ps += p2[g2][par][r] * acc[g2 * 2 + par][j][r];
        ps += __shfl_xor(ps, 16);
        ps += __shfl_xor(ps, 32);
        red[j][g2] = ps;
      }
    const int col = n0 + wn + quad * 16 + l16;  // quad writes j=quad
    const float bv = bias[col];
    float* outp = (float*)Outp;
    #pragma unroll
    for (int g2 = 0; g2 < 2; g2++)
      outp[(size_t)(bq0 + g2) * 768 + col] = red[quad][g2] + bv;
    return;
  }

  // ---- plain epilogues: C/D layout col=lane&15, row=quad*4+reg ----
  #pragma unroll
  for (int i = 0; i < 4; i++) {
    #pragma unroll
    for (int j = 0; j < 4; j++) {
      const int col = n0 + wn + j * 16 + l16;
      float bv;
      if (OUT_MODE == 3)
        bv = (col < 768) ? bias[col] : bias2[col - 768];
      else
        bv = bias[col];
      #pragma unroll
      for (int r = 0; r < 4; r++) {
        const int g = m0 + wm + i * 16 + quad * 4 + r;
        const float v = acc[i][j][r] + bv;
        if (OUT_MODE == 0) {
          ((float*)Outp)[(size_t)g * 768 + col] = v;
        } else {  // 3
          if (col < 768)
            ((short*)Outp)[(size_t)g * 768 + col] = f2bf(v);
          else
            ((float*)Outp2)[(size_t)g * 768 + (col - 768)] = v;
        }
      }
    }
  }
}

// ---------------------------------------------------------------------------
// k-proj and v-proj in one launch (blockIdx.z: 0=k row-major, 1=v vT-packed)
// vT layout: [b,s,h,d,t]; t = i*16+quad*4+r is r-consecutive -> 8B stores.
// ---------------------------------------------------------------------------
__global__ __launch_bounds__(256)
void gemm_kv(const short* __restrict__ kbf, const short* __restrict__ vbf,
             const short* __restrict__ WTk, const short* __restrict__ WTv,
             const float* __restrict__ kbias, const float* __restrict__ vbias,
             short* __restrict__ kp, short* __restrict__ vT) {
  const int K = 768;
  __shared__ __align__(16) short As[128 * 32];
  __shared__ __align__(16) short Bs[128 * 32];
  const int z = blockIdx.z;
  const short* A = z ? vbf : kbf;
  const short* WT = z ? WTv : WTk;
  const float* bias = z ? vbias : kbias;
  const int tid = threadIdx.x;
  const int m0 = blockIdx.x * 128, n0 = blockIdx.y * 128;
  const int w = tid >> 6, lane = tid & 63, quad = lane >> 4, l16 = lane & 15;
  const int wm = (w >> 1) * 64, wn = (w & 1) * 64;

  const int grow = w * 32 + (lane >> 2);
  const int kc = (lane & 3) * 8;
  const short* ag = A + (size_t)(m0 + grow) * K + kc;
  const short* bg = WT + (size_t)(n0 + grow) * K + kc;
  short* al = &As[(w * 32) * 32];
  short* bl = &Bs[(w * 32) * 32];

  const f32x4 zero4 = {0.f, 0.f, 0.f, 0.f};
  f32x4 acc[4][4];
  #pragma unroll
  for (int i = 0; i < 4; i++)
    #pragma unroll
    for (int j = 0; j < 4; j++) acc[i][j] = zero4;

  for (int k0 = 0; k0 < K; k0 += 32) {
    __syncthreads();
    async_load16(ag, al);
    async_load16(ag + (size_t)16 * K, al + 16 * 32);
    async_load16(bg, bl);
    async_load16(bg + (size_t)16 * K, bl + 16 * 32);
    ag += 32;
    bg += 32;
    __syncthreads();
    short8 af[4], bf[4];
    #pragma unroll
    for (int i = 0; i < 4; i++)
      af[i] = *(short8*)&As[(wm + i * 16 + l16) * 32 + quad * 8];
    #pragma unroll
    for (int j = 0; j < 4; j++)
      bf[j] = *(short8*)&Bs[(wn + j * 16 + l16) * 32 + quad * 8];
    #pragma unroll
    for (int i = 0; i < 4; i++)
      #pragma unroll
      for (int j = 0; j < 4; j++)
        acc[i][j] = MFMA16(af[i], bf[j], acc[i][j]);
  }

  if (z == 0) {
    #pragma unroll
    for (int i = 0; i < 4; i++)
      #pragma unroll
      for (int j = 0; j < 4; j++) {
        const int col = n0 + wn + j * 16 + l16;
        const float bv = bias[col];
        #pragma unroll
        for (int r = 0; r < 4; r++) {
          const int g = m0 + wm + i * 16 + quad * 4 + r;
          kp[(size_t)g * 768 + col] = f2bf(acc[i][j][r] + bv);
        }
      }
  } else {
    const int bs_ = (m0 + wm) >> 6;      // wave-constant
    const int hh = (n0 + wn) >> 6;       // wave-constant
    #pragma unroll
    for (int i = 0; i < 4; i++) {
      const int t0 = i * 16 + quad * 4;  // r-consecutive
      #pragma unroll
      for (int j = 0; j < 4; j++) {
        const int dd = j * 16 + l16;
        const float bv = bias[hh * 64 + dd];
        __align__(8) short tmp[4];
        #pragma unroll
        for (int r = 0; r < 4; r++) tmp[r] = f2bf(acc[i][j][r] + bv);
        *(short4v*)&vT[(((size_t)bs_ * 12 + hh) * 64 + dd) * 64 + t0] = *(short4v*)tmp;
      }
    }
  }
}

// ---------------------------------------------------------------------------
// Word-level attention, one block per (b, s, h):
//   S = Q Kt * 0.125 ; register softmax over t (+word mask) ; O = P V
// ---------------------------------------------------------------------------
__global__ __launch_bounds__(256)
void word_attn(const short* __restrict__ q_proj, const short* __restrict__ k_proj,
               const short* __restrict__ vT, const int* __restrict__ word_mask,
               short* __restrict__ wh) {
  __shared__ __align__(16) short KVs[128 * 72];  // K rows 0-63, Vt rows 64-127; O overlay
  __shared__ __align__(16) short Ps[128 * 72];   // P bf16
  short* Ks = KVs;
  short* Vs = KVs + 64 * 72;
  short* Os = KVs;

  const int bid = blockIdx.x;
  const int h = bid % 12, s = (bid / 12) % 32, b = bid / (12 * 32);
  const int tid = threadIdx.x;
  const int w = tid >> 6, lane = tid & 63, quad = lane >> 4, l16 = lane & 15;
  const f32x4 zero4 = {0.f, 0.f, 0.f, 0.f};

  // ---- stage K (tid<128) and Vt (tid>=128): 64 rows x 64 bf16 each ----
  {
    const int t2 = tid & 127;
    const int row = t2 >> 1, half = (t2 & 1) * 32;
    const short* src;
    short* dst;
    if (tid < 128) {
      src = k_proj + ((size_t)((b * 32 + s) * 64 + row)) * 768 + h * 64 + half;
      dst = &Ks[row * 72 + half];
    } else {
      src = vT + ((size_t)((b * 32 + s) * 12 + h)) * 4096 + row * 64 + half;
      dst = &Vs[row * 72 + half];
    }
    #pragma unroll
    for (int i = 0; i < 4; i++)
      *(short8*)(dst + i * 8) = *(const short8*)(src + i * 8);
  }
  __syncthreads();

  // ---- S = Q Kt ----
  f32x4 sac[2][4];
  #pragma unroll
  for (int i = 0; i < 2; i++)
    #pragma unroll
    for (int j = 0; j < 4; j++) sac[i][j] = zero4;
  {
    short8 aq[2][2], bk[4][2];
    #pragma unroll
    for (int i = 0; i < 2; i++)
      #pragma unroll
      for (int kb = 0; kb < 2; kb++)
        aq[i][kb] = *(const short8*)(q_proj +
            ((size_t)(b * 128 + w * 32 + i * 16 + l16)) * 768 + h * 64 + kb * 32 + quad * 8);
    #pragma unroll
    for (int j = 0; j < 4; j++)
      #pragma unroll
      for (int kb = 0; kb < 2; kb++)
        bk[j][kb] = *(short8*)&Ks[(j * 16 + l16) * 72 + kb * 32 + quad * 8];
    #pragma unroll
    for (int i = 0; i < 2; i++)
      #pragma unroll
      for (int j = 0; j < 4; j++) {
        sac[i][j] = MFMA16(aq[i][0], bk[j][0], sac[i][j]);
        sac[i][j] = MFMA16(aq[i][1], bk[j][1], sac[i][j]);
      }
  }

  // ---- register softmax per row (16 lanes of a quad hold one row's 64 t) ----
  {
    float wmv[4];
    const int* wmp = word_mask + (b * 32 + s) * 64;
    #pragma unroll
    for (int j = 0; j < 4; j++)
      wmv[j] = (1.0f - (float)wmp[j * 16 + l16]) * -10000.0f;
    #pragma unroll
    for (int i = 0; i < 2; i++) {
      #pragma unroll
      for (int r = 0; r < 4; r++) {
        float vv[4];
        float mx = -3.0e38f;
        #pragma unroll
        for (int j = 0; j < 4; j++) {
          const float val = sac[i][j][r] * 0.125f + wmv[j];
          vv[j] = val;
          mx = fmaxf(mx, val);
        }
        mx = fmaxf(mx, __shfl_xor(mx, 1));
        mx = fmaxf(mx, __shfl_xor(mx, 2));
        mx = fmaxf(mx, __shfl_xor(mx, 4));
        mx = fmaxf(mx, __shfl_xor(mx, 8));
        float sum = 0.f;
        #pragma unroll
        for (int j = 0; j < 4; j++) {
          vv[j] = __expf(vv[j] - mx);
          sum += vv[j];
        }
        sum += __shfl_xor(sum, 1);
        sum += __shfl_xor(sum, 2);
        sum += __shfl_xor(sum, 4);
        sum += __shfl_xor(sum, 8);
        const float inv = 1.0f / sum;
        const int row = w * 32 + i * 16 + quad * 4 + r;
        #pragma unroll
        for (int j = 0; j < 4; j++)
          Ps[row * 72 + j * 16 + l16] = f2bf(vv[j] * inv);
      }
    }
  }
  __syncthreads();

  // ---- O = P V ----
  f32x4 oac[2][4];
  #pragma unroll
  for (int i = 0; i < 2; i++)
    #pragma unroll
    for (int j = 0; j < 4; j++) oac[i][j] = zero4;
  {
    short8 ap[2][2], bv[4][2];
    #pragma unroll
    for (int i = 0; i < 2; i++)
      #pragma unroll
      for (int kb = 0; kb < 2; kb++)
        ap[i][kb] = *(short8*)&Ps[(w * 32 + i * 16 + l16) * 72 + kb * 32 + quad * 8];
    #pragma unroll
    for (int j = 0; j < 4; j++)
      #pragma unroll
      for (int kb = 0; kb < 2; kb++)
        bv[j][kb] = *(short8*)&Vs[(j * 16 + l16) * 72 + kb * 32 + quad * 8];
    #pragma unroll
    for (int i = 0; i < 2; i++)
      #pragma unroll
      for (int j = 0; j < 4; j++) {
        oac[i][j] = MFMA16(ap[i][0], bv[j][0], oac[i][j]);
        oac[i][j] = MFMA16(ap[i][1], bv[j][1], oac[i][j]);
      }
  }
  __syncthreads();  // K/V reads complete before O overlay write
  #pragma unroll
  for (int i = 0; i < 2; i++)
    #pragma unroll
    for (int j = 0; j < 4; j++)
      #pragma unroll
      for (int r = 0; r < 4; r++)
        Os[(w * 32 + i * 16 + quad * 4 + r) * 72 + j * 16 + l16] = f2bf(oac[i][j][r]);
  __syncthreads();

  {
    const int row = tid >> 1, half = (tid & 1) * 32;
    short* dst = wh + (((size_t)(b * 128 + row)) * 32 + s) * 768 + h * 64 + half;
    const short* src = &Os[row * 72 + half];
    #pragma unroll
    for (int i = 0; i < 4; i++)
      *(short8*)(dst + i * 8) = *(const short8*)(src + i * 8);
  }
}

// ---------------------------------------------------------------------------
// Sentence-attention probabilities: probs2[bq, h, s], one block per (b, q)
// ---------------------------------------------------------------------------
__global__ __launch_bounds__(256)
void sent_probs(const float* __restrict__ sq, const float* __restrict__ sk,
                const int* __restrict__ sent_mask, float* __restrict__ probs2) {
  __shared__ float sc[12 * 33];
  const int bid = blockIdx.x;
  const int b = bid >> 7, q = bid & 127;
  const int tid = threadIdx.x;

  for (int p = tid; p < 384; p += 256) {
    const int hh = p >> 5, ss = p & 31;
    const float4* a = (const float4*)(sq + ((size_t)(b * 128 + q)) * 768 + hh * 64);
    const float4* c = (const float4*)(sk + ((size_t)(b * 32 + ss)) * 768 + hh * 64);
    float d = 0.f;
    #pragma unroll
    for (int i = 0; i < 16; i++) {
      const float4 av = a[i], cv = c[i];
      d += av.x * cv.x + av.y * cv.y + av.z * cv.z + av.w * cv.w;
    }
    d = d * 0.125f + (1.0f - (float)sent_mask[(b * 128 + q) * 32 + ss]) * -10000.0f;
    sc[hh * 33 + ss] = d;
  }
  __syncthreads();
  if (tid < 12) {
    float mx = -3.0e38f;
    for (int ss = 0; ss < 32; ss++) mx = fmaxf(mx, sc[tid * 33 + ss]);
    float sum = 0.f;
    for (int ss = 0; ss < 32; ss++) {
      const float e = __expf(sc[tid * 33 + ss] - mx);
      sc[tid * 33 + ss] = e;
      sum += e;
    }
    const float inv = 1.0f / sum;
    for (int ss = 0; ss < 32; ss++) sc[tid * 33 + ss] *= inv;
  }
  __syncthreads();
  for (int p = tid; p < 384; p += 256) {
    const int hh = p >> 5, ss = p & 31;
    probs2[((size_t)bid * 12 + hh) * 32 + ss] = sc[hh * 33 + ss];
  }
}

// ---------------------------------------------------------------------------
extern "C" void kernel_launch(void* const* d_in, const int* in_sizes, int n_in,
                              void* d_out, int out_size, void* d_ws, size_t ws_size,
                              hipStream_t stream) {
  (void)in_sizes; (void)n_in; (void)out_size; (void)ws_size;
  const float* q_in      = (const float*)d_in[0];   // [8,128,768]
  const float* k_in      = (const float*)d_in[1];   // [8,32,64,768]
  const float* v_in      = (const float*)d_in[2];   // [8,32,64,768]
  const float* kvec      = (const float*)d_in[3];   // [8,32,768]
  const int*   word_mask = (const int*)d_in[4];     // [8,32,64]
  const int*   sent_mask = (const int*)d_in[5];     // [1024,32]
  const float* wq_w = (const float*)d_in[6],  *wq_b = (const float*)d_in[7];
  const float* wk_w = (const float*)d_in[8],  *wk_b = (const float*)d_in[9];
  const float* wv_w = (const float*)d_in[10], *wv_b = (const float*)d_in[11];
  const float* sq_w = (const float*)d_in[12], *sq_b = (const float*)d_in[13];
  const float* sk_w = (const float*)d_in[14], *sk_b = (const float*)d_in[15];
  const float* sv_w = (const float*)d_in[16], *sv_b = (const float*)d_in[17];
  float* out = (float*)d_out;

  char* ws = (char*)d_ws;
  size_t off = 0;
  auto alloc = [&](size_t bytes) -> void* {
    void* p = ws + off;
    off += (bytes + 255) & ~(size_t)255;
    return p;
  };
  short* WT  = (short*)alloc((size_t)6 * 768 * 768 * 2);   //  7.1 MB (wq,sq,wk,wv,sk,sv)
  short* qbf = (short*)alloc((size_t)1024 * 768 * 2);
  short* kbf = (short*)alloc((size_t)16384 * 768 * 2);
  short* vbf = (short*)alloc((size_t)16384 * 768 * 2);
  short* kvb = (short*)alloc((size_t)256 * 768 * 2);
  short* qp  = (short*)alloc((size_t)1024 * 768 * 2);
  short* kp  = (short*)alloc((size_t)16384 * 768 * 2);
  short* vT  = (short*)alloc((size_t)16384 * 768 * 2);     // [b,s,h,d,t]
  float* sqp = (float*)alloc((size_t)1024 * 768 * 4);
  float* skp = (float*)alloc((size_t)256 * 768 * 4);
  short* wh  = (short*)alloc((size_t)32768 * 768 * 2);     // 50.3 MB
  float* pr2 = (float*)alloc((size_t)1024 * 12 * 32 * 4);  //  1.6 MB

  const int WELEM = 768 * 768;

  transpose_w6<<<dim3(24, 24, 6), dim3(32, 8), 0, stream>>>(
      wq_w, sq_w, wk_w, wv_w, sk_w, sv_w, WT);
  cvt_all<<<dim3(12768), 256, 0, stream>>>(q_in, k_in, v_in, kvec, qbf, kbf, vbf, kvb);

  // projections
  gemm_lds<3><<<dim3(8, 12), 256, 0, stream>>>(qbf, WT + 0 * WELEM, wq_b, sq_b,
                                               nullptr, qp, sqp);
  gemm_kv<<<dim3(128, 6, 2), 256, 0, stream>>>(kbf, vbf, WT + 2 * WELEM, WT + 3 * WELEM,
                                               wk_b, wv_b, kp, vT);
  gemm_lds<0><<<dim3(2, 6), 256, 0, stream>>>(kvb, WT + 4 * WELEM, sk_b, nullptr,
                                              nullptr, skp, nullptr);

  // word-level attention -> wh [(b,q,s), 768] bf16
  word_attn<<<dim3(3072), 256, 0, stream>>>(qp, kp, vT, word_mask, wh);

  // sentence-attention probabilities
  sent_probs<<<dim3(1024), 256, 0, stream>>>(sqp, skp, sent_mask, pr2);

  // sv GEMM with fused sentence-attention contraction -> out (fp32)
  gemm_lds<4><<<dim3(256, 6), 256, 0, stream>>>(wh, WT + 5 * WELEM, sv_b, nullptr,
                                                pr2, out, nullptr);
}